// Round 3
// baseline (454.520 us; speedup 1.0000x reference)
//
#include <hip/hip_runtime.h>
#include <hip/hip_bf16.h>
#include <cmath>

typedef _Float16 f16x8 __attribute__((ext_vector_type(8)));
typedef float f32x4 __attribute__((ext_vector_type(4)));

#define T_SEQ 2048
#define C_DIM 768
#define H_NUM 12
#define NX (8192 * 768)
#define NW (768 * 768)

__device__ __forceinline__ unsigned short f2h(float f) {
    _Float16 h = (_Float16)f;
    return __builtin_bit_cast(unsigned short, h);
}

// async global->LDS 16B DMA (wave-uniform base + lane*16)
__device__ __forceinline__ void gld16(const unsigned short* g, unsigned short* l) {
    __builtin_amdgcn_global_load_lds(
        (const __attribute__((address_space(1))) unsigned int*)g,
        (__attribute__((address_space(3))) unsigned int*)l, 16, 0, 0);
}

// Ps swizzled index within a [16][64] tile (8-short chunks XOR row)
__device__ __forceinline__ int ps_idx(int row, int col) {
    return row * 64 + (((col >> 3) ^ (row & 7)) << 3) + (col & 7);
}

// ---------------- cast fp32 -> fp16 with k-chunk swizzle ----------------
// element (r, k) of a row-major [rows][768] matrix stored at column
// (k & ~31) | ((((k>>3)&3) ^ (r&3)) << 3) | (k&7)
__global__ __launch_bounds__(256)
void cast_swz(const float* __restrict__ src, unsigned short* __restrict__ dst) {
    int cidx = blockIdx.x * 256 + threadIdx.x;   // chunk of 8 elements
    int row = cidx / 96;                          // 96 chunks per 768-row
    int cp = cidx - row * 96;
    int dchunk = row * 96 + (cp & ~3) + ((cp & 3) ^ (row & 3));
    const float* s = src + (size_t)cidx * 8;
    float4 v0 = *(const float4*)s, v1 = *(const float4*)(s + 4);
    ushort4 a, b;
    a.x = f2h(v0.x); a.y = f2h(v0.y); a.z = f2h(v0.z); a.w = f2h(v0.w);
    b.x = f2h(v1.x); b.y = f2h(v1.y); b.z = f2h(v1.z); b.w = f2h(v1.w);
    unsigned short* d = dst + (size_t)dchunk * 8;
    *(ushort4*)d = a;
    *(ushort4*)(d + 4) = b;
}

// ---------------- transpose + cast W: w[k][n] f32 -> wt[n][k] f16, swizzled ----------------
// grid (12, 12, 4), block 256
__global__ __launch_bounds__(256)
void transpose_cast(const float* __restrict__ w0, const float* __restrict__ w1,
                    const float* __restrict__ w2, const float* __restrict__ w3,
                    unsigned short* __restrict__ dst_base) {
    const float* src = (blockIdx.z == 0) ? w0 : (blockIdx.z == 1) ? w1
                     : (blockIdx.z == 2) ? w2 : w3;
    unsigned short* dst = dst_base + (size_t)blockIdx.z * NW;
    __shared__ float T[64][65];
    const int k0 = blockIdx.x * 64, n0 = blockIdx.y * 64;
    const int tid = threadIdx.x;
    {
        int rowb = tid >> 4, c4 = (tid & 15) * 4;
#pragma unroll
        for (int i = 0; i < 4; ++i) {
            int row = rowb + i * 16;
            float4 v = *(const float4*)&src[(size_t)(k0 + row) * C_DIM + n0 + c4];
            T[row][c4] = v.x; T[row][c4 + 1] = v.y; T[row][c4 + 2] = v.z; T[row][c4 + 3] = v.w;
        }
    }
    __syncthreads();
    {
        int n = tid & 63, kseg = (tid >> 6) * 16;
        int n_glob = n0 + n;
        unsigned short tmp[16];
#pragma unroll
        for (int j = 0; j < 16; ++j) tmp[j] = f2h(T[kseg + j][n]);
        int base = k0 + (kseg & 32);
        int sub = (kseg >> 3) & 3;
        unsigned short* drow = dst + (size_t)n_glob * C_DIM + base;
        *(uint4*)&drow[(sub ^ (n_glob & 3)) << 3]       = *(uint4*)&tmp[0];
        *(uint4*)&drow[((sub + 1) ^ (n_glob & 3)) << 3] = *(uint4*)&tmp[8];
    }
}

// ---------------- QKV GEMM 128x128 + fused RoPE / V-transpose ----------------
// grid (6, 64, 3), block 256; inputs pre-swizzled, staged via global_load_lds
__global__ __launch_bounds__(256, 3)
void qkv_gemm(const unsigned short* __restrict__ xb,
              const unsigned short* __restrict__ wt,   // [3][n][k] swizzled
              unsigned short* __restrict__ q_ws,       // [B,H,T,D]
              unsigned short* __restrict__ k_ws,       // [B,H,T,D]
              unsigned short* __restrict__ vt_ws) {    // [B,H,D,T]
    const int which = blockIdx.z;
    const unsigned short* W = wt + (size_t)which * NW;
    const int n0 = blockIdx.x * 128, m0 = blockIdx.y * 128;

    __shared__ __align__(16) unsigned short As[128 * 32];
    __shared__ __align__(16) unsigned short Bs[128 * 32];

    const int tid = threadIdx.x, lane = tid & 63, w = tid >> 6;
    const int quad = lane >> 4, l16 = lane & 15;
    const int wm = (w >> 1) * 64, wn = (w & 1) * 64;

    f32x4 acc[4][4] = {};
    const int e0 = tid, e1 = 256 + tid;
    const int r0 = e0 >> 2, c0 = (e0 & 3) * 8;
    const int r1 = e1 >> 2, c1 = (e1 & 3) * 8;

    for (int k0 = 0; k0 < C_DIM; k0 += 32) {
        __syncthreads();
        gld16(xb + (size_t)(m0 + r0) * C_DIM + k0 + c0, &As[e0 * 8]);
        gld16(xb + (size_t)(m0 + r1) * C_DIM + k0 + c1, &As[e1 * 8]);
        gld16(W  + (size_t)(n0 + r0) * C_DIM + k0 + c0, &Bs[e0 * 8]);
        gld16(W  + (size_t)(n0 + r1) * C_DIM + k0 + c1, &Bs[e1 * 8]);
        __syncthreads();
        f16x8 af[4], bf[4];
#pragma unroll
        for (int mt = 0; mt < 4; ++mt) {
            int r = wm + mt * 16 + l16;
            af[mt] = *(const f16x8*)&As[r * 32 + ((quad ^ (r & 3)) << 3)];
        }
#pragma unroll
        for (int nt = 0; nt < 4; ++nt) {
            int r = wn + nt * 16 + l16;
            bf[nt] = *(const f16x8*)&Bs[r * 32 + ((quad ^ (r & 3)) << 3)];
        }
#pragma unroll
        for (int mt = 0; mt < 4; ++mt)
#pragma unroll
            for (int nt = 0; nt < 4; ++nt)
                acc[mt][nt] = __builtin_amdgcn_mfma_f32_16x16x32_f16(af[mt], bf[nt], acc[mt][nt], 0, 0, 0);
    }

    const int head = blockIdx.x * 2 + (w & 1);   // wave's 64 cols == one head

    if (which < 2) {
        unsigned short* dst = (which == 0) ? q_ws : k_ws;
#pragma unroll
        for (int ntp = 0; ntp < 2; ++ntp) {
            int d1 = ntp * 16 + l16;   // 0..31
            float invf = __expf(-0.28782313662425572f * (float)d1);
#pragma unroll
            for (int mt = 0; mt < 4; ++mt)
#pragma unroll
                for (int reg = 0; reg < 4; ++reg) {
                    int m = m0 + wm + mt * 16 + quad * 4 + reg;
                    int t = m & (T_SEQ - 1), bb = m >> 11;
                    float sn, cs;
                    __sincosf((float)t * invf, &sn, &cs);
                    float v1 = acc[mt][ntp][reg], v2 = acc[mt][ntp + 2][reg];
                    float o1 = v1 * cs - v2 * sn;
                    float o2 = v2 * cs + v1 * sn;
                    if (which == 0) { o1 *= 0.125f; o2 *= 0.125f; }
                    size_t o = ((size_t)(bb * H_NUM + head) * T_SEQ + t) * 64 + d1;
                    dst[o] = f2h(o1);
                    dst[o + 32] = f2h(o2);
                }
        }
    } else {
#pragma unroll
        for (int nt = 0; nt < 4; ++nt) {
            int d = nt * 16 + l16;
#pragma unroll
            for (int mt = 0; mt < 4; ++mt) {
                int m = m0 + wm + mt * 16 + quad * 4;
                int t = m & (T_SEQ - 1), bb = m >> 11;
                ushort4 pk;
                pk.x = f2h(acc[mt][nt][0]); pk.y = f2h(acc[mt][nt][1]);
                pk.z = f2h(acc[mt][nt][2]); pk.w = f2h(acc[mt][nt][3]);
                *(ushort4*)&vt_ws[((size_t)(bb * H_NUM + head) * 64 + d) * T_SEQ + t] = pk;
            }
        }
    }
}

// ---------------- causal flash attention: 1 q-tile/block, grid 1536 ----------------
__global__ __launch_bounds__(256, 5)
void flash_attn(const unsigned short* __restrict__ q_ws,
                const unsigned short* __restrict__ k_ws,
                const unsigned short* __restrict__ vt_ws,
                unsigned short* __restrict__ attn_out) {   // [B][T][C] f16 swizzled
    __shared__ __align__(16) unsigned short Ps[4 * 16 * 64];

    const int pid = blockIdx.x;
    const int xcd = pid & 7, slot = pid >> 3;   // cluster bh per XCD
    const int bh = xcd * 6 + (slot >> 5);
    const int qt = 31 - (slot & 31);            // LPT: long blocks dispatch first
    const int b = bh / H_NUM, h = bh % H_NUM;

    const int tid = threadIdx.x, lane = tid & 63, w = tid >> 6;
    const int quad = lane >> 4, l16 = lane & 15;
    const size_t base = (size_t)bh * (T_SEQ * 64);

    const unsigned short* qp = q_ws + base + (size_t)(qt * 64 + w * 16 + l16) * 64 + quad * 8;
    f16x8 aq0 = *(const f16x8*)(qp);
    f16x8 aq1 = *(const f16x8*)(qp + 32);

    f32x4 acc[4] = {};
    float lsum[4] = {};
    unsigned short* pb = Ps + w * 1024;
    const int swz = l16 & 7;
    const int rd0 = l16 * 64 + ((quad ^ swz) << 3);
    const int rd1 = l16 * 64 + (((quad + 4) ^ swz) << 3);

    for (int kt = 0; kt <= qt; ++kt) {
        const unsigned short* kb = k_ws + base + (size_t)kt * (64 * 64);
        const unsigned short* vb = vt_ws + base + (size_t)kt * 64;
        f16x8 bk[4][2];
#pragma unroll
        for (int nt = 0; nt < 4; ++nt) {
            const unsigned short* kr = kb + (nt * 16 + l16) * 64 + quad * 8;
            bk[nt][0] = *(const f16x8*)(kr);
            bk[nt][1] = *(const f16x8*)(kr + 32);
        }
        f32x4 s[4] = {};
#pragma unroll
        for (int nt = 0; nt < 4; ++nt) {
            s[nt] = __builtin_amdgcn_mfma_f32_16x16x32_f16(aq0, bk[nt][0], s[nt], 0, 0, 0);
            s[nt] = __builtin_amdgcn_mfma_f32_16x16x32_f16(aq1, bk[nt][1], s[nt], 0, 0, 0);
        }
        f16x8 bv[4][2];
#pragma unroll
        for (int nt = 0; nt < 4; ++nt) {
            const unsigned short* vr = vb + (size_t)(nt * 16 + l16) * T_SEQ + quad * 8;
            bv[nt][0] = *(const f16x8*)(vr);
            bv[nt][1] = *(const f16x8*)(vr + 32);
        }
        if (kt == qt) {
#pragma unroll
            for (int nt = 0; nt < 4; ++nt)
#pragma unroll
                for (int reg = 0; reg < 4; ++reg)
                    if (nt * 16 + l16 > w * 16 + quad * 4 + reg) s[nt][reg] = -1e30f;
        }
#pragma unroll
        for (int nt = 0; nt < 4; ++nt)
#pragma unroll
            for (int reg = 0; reg < 4; ++reg) {
                float p = __expf(fminf(s[nt][reg], 11.0f));
                lsum[reg] += p;
                pb[ps_idx(quad * 4 + reg, nt * 16 + l16)] = f2h(p);
            }
        f16x8 ap0 = *(const f16x8*)(pb + rd0);
        f16x8 ap1 = *(const f16x8*)(pb + rd1);
#pragma unroll
        for (int nt = 0; nt < 4; ++nt) {
            acc[nt] = __builtin_amdgcn_mfma_f32_16x16x32_f16(ap0, bv[nt][0], acc[nt], 0, 0, 0);
            acc[nt] = __builtin_amdgcn_mfma_f32_16x16x32_f16(ap1, bv[nt][1], acc[nt], 0, 0, 0);
        }
    }

#pragma unroll
    for (int reg = 0; reg < 4; ++reg) {
        float v = lsum[reg];
        v += __shfl_xor(v, 1); v += __shfl_xor(v, 2);
        v += __shfl_xor(v, 4); v += __shfl_xor(v, 8);
        lsum[reg] = 1.0f / v;
    }
#pragma unroll
    for (int nt = 0; nt < 4; ++nt)
#pragma unroll
        for (int reg = 0; reg < 4; ++reg) {
            int t = qt * 64 + w * 16 + quad * 4 + reg;
            int col = h * 64 + nt * 16 + l16;
            // swizzled store for out_proj's DMA staging (row parity = reg)
            int csw = (col & ~31) | (((((col >> 3) & 3) ^ (reg & 3)) << 3)) | (col & 7);
            attn_out[(size_t)(b * T_SEQ + t) * C_DIM + csw] = f2h(acc[nt][reg] * lsum[reg]);
        }
}

// ---------------- output projection 128x128 (f16 swizzled in, f32 out) ----------------
// grid (6, 64), block 256
__global__ __launch_bounds__(256, 3)
void out_proj(const unsigned short* __restrict__ ab,
              const unsigned short* __restrict__ wt_o,
              float* __restrict__ out) {
    const int n0 = blockIdx.x * 128, m0 = blockIdx.y * 128;
    __shared__ __align__(16) unsigned short As[128 * 32];
    __shared__ __align__(16) unsigned short Bs[128 * 32];

    const int tid = threadIdx.x, lane = tid & 63, w = tid >> 6;
    const int quad = lane >> 4, l16 = lane & 15;
    const int wm = (w >> 1) * 64, wn = (w & 1) * 64;

    f32x4 acc[4][4] = {};
    const int e0 = tid, e1 = 256 + tid;
    const int r0 = e0 >> 2, c0 = (e0 & 3) * 8;
    const int r1 = e1 >> 2, c1 = (e1 & 3) * 8;

    for (int k0 = 0; k0 < C_DIM; k0 += 32) {
        __syncthreads();
        gld16(ab   + (size_t)(m0 + r0) * C_DIM + k0 + c0, &As[e0 * 8]);
        gld16(ab   + (size_t)(m0 + r1) * C_DIM + k0 + c1, &As[e1 * 8]);
        gld16(wt_o + (size_t)(n0 + r0) * C_DIM + k0 + c0, &Bs[e0 * 8]);
        gld16(wt_o + (size_t)(n0 + r1) * C_DIM + k0 + c1, &Bs[e1 * 8]);
        __syncthreads();
        f16x8 af[4], bf[4];
#pragma unroll
        for (int mt = 0; mt < 4; ++mt) {
            int r = wm + mt * 16 + l16;
            af[mt] = *(const f16x8*)&As[r * 32 + ((quad ^ (r & 3)) << 3)];
        }
#pragma unroll
        for (int nt = 0; nt < 4; ++nt) {
            int r = wn + nt * 16 + l16;
            bf[nt] = *(const f16x8*)&Bs[r * 32 + ((quad ^ (r & 3)) << 3)];
        }
#pragma unroll
        for (int mt = 0; mt < 4; ++mt)
#pragma unroll
            for (int nt = 0; nt < 4; ++nt)
                acc[mt][nt] = __builtin_amdgcn_mfma_f32_16x16x32_f16(af[mt], bf[nt], acc[mt][nt], 0, 0, 0);
    }

#pragma unroll
    for (int mt = 0; mt < 4; ++mt)
#pragma unroll
        for (int nt = 0; nt < 4; ++nt)
#pragma unroll
            for (int reg = 0; reg < 4; ++reg) {
                int m = m0 + wm + mt * 16 + quad * 4 + reg;
                int n = n0 + wn + nt * 16 + l16;
                out[(size_t)m * C_DIM + n] = acc[mt][nt][reg];
            }
}

// ---------------- launch ----------------
extern "C" void kernel_launch(void* const* d_in, const int* in_sizes, int n_in,
                              void* d_out, int out_size, void* d_ws, size_t ws_size,
                              hipStream_t stream) {
    const float* x  = (const float*)d_in[0];
    const float* wq = (const float*)d_in[1];
    const float* wk = (const float*)d_in[2];
    const float* wv = (const float*)d_in[3];
    const float* wo = (const float*)d_in[4];
    float* out = (float*)d_out;

    unsigned short* xb    = (unsigned short*)d_ws;   // NX (swizzled); reused as attn
    unsigned short* wt    = xb + NX;                 // 4*NW swizzled [n][k]
    unsigned short* q_ws  = wt + 4 * (size_t)NW;     // NX
    unsigned short* k_ws  = q_ws + NX;               // NX
    unsigned short* vt_ws = k_ws + NX;               // NX
    unsigned short* attn  = xb;                      // alias: xb dead after qkv_gemm

    cast_swz<<<NX / 2048, 256, 0, stream>>>(x, xb);
    transpose_cast<<<dim3(12, 12, 4), 256, 0, stream>>>(wq, wk, wv, wo, wt);
    qkv_gemm<<<dim3(6, 64, 3), 256, 0, stream>>>(xb, wt, q_ws, k_ws, vt_ws);
    flash_attn<<<1536, 256, 0, stream>>>(q_ws, k_ws, vt_ws, attn);
    out_proj<<<dim3(6, 64), 256, 0, stream>>>(attn, wt + 3 * (size_t)NW, out);
}